// Round 12
// baseline (904.700 us; speedup 1.0000x reference)
//
#include <hip/hip_runtime.h>

// OnsetLSTM: 2-layer LSTM, B=256, T=512, D=160, H=128, fp32 in/out.
//
// Architecture: x-side gate pre-acts (bias folded) via MFMA GEMM; recurrence
// keeps only W_hh in registers (thread=(cell c, K-half s), 128 f16 pairs).
// Chunked layer pipeline NC=4: L0 chunk c || L1 chunk c-1.
//
// R12 changes (R9/R10/R11 all ~3450cy/step regardless of structure):
//  1. RAW barrier (lgkmcnt(0)+s_barrier asm): kills the per-step vmcnt(0)
//     drain hipcc emits before __syncthreads -> h1 store-acks and Gx gathers
//     stay in flight across steps.
//  2. 16 accumulators (4/gate): dependent dot2 chain depth 32 -> 8.
//  3. waves_per_eu(1,1) at 256thr + full-group Gx prefetch (R9 depth).

typedef _Float16 f16;
typedef _Float16 f16x8 __attribute__((ext_vector_type(8)));
typedef float f32x4 __attribute__((ext_vector_type(4)));

#define B_  256
#define T_  512
#define HID 128
#define NG  512
#define KX0 160
#define NC  4
#define TC  128   // T_/NC

// step barrier WITHOUT vmcnt drain: LDS ops complete, VMEM stays in flight
#define STEP_BARRIER() asm volatile("s_waitcnt lgkmcnt(0)\n\ts_barrier" ::: "memory")

static __device__ __forceinline__ unsigned pack2(float a, float b) {
  union { f16 h[2]; unsigned u; } v;
  v.h[0] = (f16)a; v.h[1] = (f16)b;
  return v.u;
}

// v_dot2_f32_f16: d = a.h0*b.h0 + a.h1*b.h1 + c (CDNA4 VOP3P)
static __device__ __forceinline__ float dot2f(unsigned a, unsigned b, float c) {
  float d;
  asm("v_dot2_f32_f16 %0, %1, %2, %3" : "=v"(d) : "v"(a), "v"(b), "v"(c));
  return d;
}

static __device__ __forceinline__ float fast_rcp(float x) {
#if __has_builtin(__builtin_amdgcn_rcpf)
  return __builtin_amdgcn_rcpf(x);
#else
  return 1.0f / x;
#endif
}
static __device__ __forceinline__ float fast_exp2(float x) {
#if __has_builtin(__builtin_amdgcn_exp2f)
  return __builtin_amdgcn_exp2f(x);
#else
  return exp2f(x);
#endif
}
static __device__ __forceinline__ float sigm(float x) {
  return fast_rcp(1.0f + fast_exp2(x * -1.44269504f));
}
static __device__ __forceinline__ float tanh_f(float x) {
  float e = fast_exp2(x * 2.885390082f);
  return 1.0f - 2.0f * fast_rcp(e + 1.0f);
}

// one butterfly stage over lane^1 (the two K-halves of a cell)
static __device__ __forceinline__ float qp_add1(float v) {
  int iv = __builtin_bit_cast(int, v);
  int t = __builtin_amdgcn_update_dpp(iv, iv, 0xB1, 0xF, 0xF, true);
  return v + __builtin_bit_cast(float, t);
}

// extract f16 #j (compile-time after unroll) from an 8-half batch
static __device__ __forceinline__ float gxval(const uint4& g, int j) {
  unsigned w = (j >> 1) == 0 ? g.x : (j >> 1) == 1 ? g.y : (j >> 1) == 2 ? g.z : g.w;
  unsigned hs = (j & 1) ? (w >> 16) : (w & 0xffffu);
  f16 v = __builtin_bit_cast(f16, (unsigned short)hs);
  return (float)v;
}

// ======================= GEMM: Gx = A @ W^T (+bias), t-transposed store =====
template <int K, bool AF16>
__global__ __launch_bounds__(256) void gemm_xw(
    const void* __restrict__ Aptr, size_t bStride,
    const float* __restrict__ W,
    const float* __restrict__ bihp, const float* __restrict__ bhhp,
    f16* __restrict__ D) {
  constexpr int KP = K + 8;
  __shared__ f16 As[128][KP];
  __shared__ f16 Bs[64][KP];
  const int tid = threadIdx.x;
  const int mtile = blockIdx.x, ntile = blockIdx.y;

  if (AF16) {
    const f16* A = (const f16*)Aptr;
    for (int i = tid; i < 128 * (K / 8); i += 256) {
      int r = i / (K / 8), kk = (i % (K / 8)) * 8;
      size_t grow = (size_t)mtile * 128 + r;
      uint4 v = *(const uint4*)(A + grow * K + kk);
      *(uint4*)&As[r][kk] = v;
    }
  } else {
    const float* A = (const float*)Aptr;
    for (int i = tid; i < 128 * (K / 4); i += 256) {
      int r = i / (K / 4), kk = (i % (K / 4)) * 4;
      int grow = mtile * 128 + r;
      int bb = grow >> 7, tt = grow & (TC - 1);
      const float* p = A + (size_t)bb * bStride + (size_t)tt * K + kk;
      float4 v = *(const float4*)p;
      uint2 u;
      u.x = pack2(v.x, v.y);
      u.y = pack2(v.z, v.w);
      *(uint2*)&As[r][kk] = u;
    }
  }
  for (int i = tid; i < 64 * (K / 4); i += 256) {
    int r = i / (K / 4), kk = (i % (K / 4)) * 4;
    const float* p = W + (size_t)(ntile * 64 + r) * K + kk;
    float4 v = *(const float4*)p;
    uint2 u;
    u.x = pack2(v.x, v.y);
    u.y = pack2(v.z, v.w);
    *(uint2*)&Bs[r][kk] = u;
  }
  __syncthreads();

  const int w = tid >> 6, l = tid & 63;
  const int lr = l & 15, lg = l >> 4;
  f32x4 acc[2][4] = {};
#pragma unroll
  for (int ks = 0; ks < K / 32; ++ks) {
    f16x8 a0 = *(const f16x8*)&As[w * 32 + lr][ks * 32 + lg * 8];
    f16x8 a1 = *(const f16x8*)&As[w * 32 + 16 + lr][ks * 32 + lg * 8];
    f16x8 bf[4];
#pragma unroll
    for (int nj = 0; nj < 4; ++nj)
      bf[nj] = *(const f16x8*)&Bs[nj * 16 + lr][ks * 32 + lg * 8];
#pragma unroll
    for (int nj = 0; nj < 4; ++nj) {
      acc[0][nj] = __builtin_amdgcn_mfma_f32_16x16x32_f16(a0, bf[nj], acc[0][nj], 0, 0, 0);
      acc[1][nj] = __builtin_amdgcn_mfma_f32_16x16x32_f16(a1, bf[nj], acc[1][nj], 0, 0, 0);
    }
  }
  // C/D layout (m89): col = lane&15, row = (lane>>4)*4 + q. Rows are t.
#pragma unroll
  for (int mi = 0; mi < 2; ++mi) {
#pragma unroll
    for (int nj = 0; nj < 4; ++nj) {
      int col = ntile * 64 + nj * 16 + lr;
      float bsum = bihp[col] + bhhp[col];
      int cell = col & 127, gate = col >> 7;
      int rowbase = mtile * 128 + w * 32 + mi * 16 + lg * 4;
      int bb = rowbase >> 7, tt = rowbase & (TC - 1);
      unsigned lo = pack2(acc[mi][nj][0] + bsum, acc[mi][nj][1] + bsum);
      unsigned hi = pack2(acc[mi][nj][2] + bsum, acc[mi][nj][3] + bsum);
      size_t idx = (((size_t)bb * HID + cell) * 4 + gate) * TC + tt;
      uint2 u; u.x = lo; u.y = hi;
      *(uint2*)(D + idx) = u;
    }
  }
}

// ======================= Recurrence (chunk, possibly 2 layers) ==============
struct RecArgs {
  const f16* Gx;      // [(b*128+cell)*4+gate][TC], bias included
  const float* Whh;   // [512][128]
  const float* hin; const float* cin;   // [B][128] f32
  float* hst; float* cst;               // [B][128] f32
  f16* h1out;                            // [B][TC][128] or null
  float* fin;                            // [B][128] or null
};

__global__ __launch_bounds__(256) __attribute__((amdgpu_waves_per_eu(1, 1)))
void lstm_rec2(RecArgs A, RecArgs B, int nA) {
  const RecArgs& P = ((int)blockIdx.x < nA) ? A : B;
  const int b = ((int)blockIdx.x < nA) ? blockIdx.x : blockIdx.x - nA;
  const int tid = threadIdx.x;
  const int c = tid >> 1, s = tid & 1;  // cell, K-half
  __shared__ unsigned hbuf[2][64];

  // W_hh rows for all 4 gates of cell c, pairs [32s, 32s+32) -> 128 VGPRs
  unsigned wh[4][32];
#pragma unroll
  for (int g = 0; g < 4; ++g) {
    const int r = g * HID + c;
#pragma unroll
    for (int j = 0; j < 32; ++j) {
      int p = 32 * s + j;
      wh[g][j] = pack2(P.Whh[(size_t)r * HID + 2 * p], P.Whh[(size_t)r * HID + 2 * p + 1]);
    }
  }
  float cstate = P.cin[b * HID + c];
  if (tid < 64)
    hbuf[0][tid] = pack2(P.hin[b * HID + 2 * tid], P.hin[b * HID + 2 * tid + 1]);

  const f16* gxb = P.Gx + ((size_t)b * HID + c) * 4 * TC;
  f16* h1x = P.h1out ? P.h1out + (size_t)b * TC * HID + c : (f16*)nullptr;

  uint4 gA[4], gB[4];
#pragma unroll
  for (int g = 0; g < 4; ++g) gA[g] = *(const uint4*)(gxb + (size_t)g * TC + 0);
  __syncthreads();  // prologue: full sync once

  float hprev = 0.f;

  auto STEP = [&](const uint4 (&gx)[4], int t, int j) {
    // h1 store floats free across steps (no vm drain at the raw barrier)
    if (h1x && s == 0 && t > 0) h1x[(size_t)(t - 1) * HID] = (f16)hprev;
    const uint4* hs4 = (const uint4*)&hbuf[t & 1][32 * s];
    float acc[4][4] = {{0.f, 0.f, 0.f, 0.f}, {0.f, 0.f, 0.f, 0.f},
                       {0.f, 0.f, 0.f, 0.f}, {0.f, 0.f, 0.f, 0.f}};
#pragma unroll
    for (int k = 0; k < 8; ++k) {
      uint4 v = hs4[k];
#pragma unroll
      for (int g = 0; g < 4; ++g) {
        acc[g][0] = dot2f(v.x, wh[g][4 * k + 0], acc[g][0]);
        acc[g][1] = dot2f(v.y, wh[g][4 * k + 1], acc[g][1]);
        acc[g][2] = dot2f(v.z, wh[g][4 * k + 2], acc[g][2]);
        acc[g][3] = dot2f(v.w, wh[g][4 * k + 3], acc[g][3]);
      }
    }
    float ai = (acc[0][0] + acc[0][1]) + (acc[0][2] + acc[0][3]);
    float af = (acc[1][0] + acc[1][1]) + (acc[1][2] + acc[1][3]);
    float ag = (acc[2][0] + acc[2][1]) + (acc[2][2] + acc[2][3]);
    float ao = (acc[3][0] + acc[3][1]) + (acc[3][2] + acc[3][3]);
    // single butterfly stage (lane^1): both K-halves get full sums
    ai = qp_add1(ai); af = qp_add1(af); ag = qp_add1(ag); ao = qp_add1(ao);

    float iv = sigm(ai + gxval(gx[0], j));
    float fv = sigm(af + gxval(gx[1], j));
    float gv = tanh_f(ag + gxval(gx[2], j));
    float ov = sigm(ao + gxval(gx[3], j));
    cstate = fv * cstate + iv * gv;
    float h = ov * tanh_f(cstate);
    if (s == 0) ((f16*)&hbuf[(t + 1) & 1][0])[c] = (f16)h;
    hprev = h;
    STEP_BARRIER();
  };

#pragma unroll 1
  for (int t0 = 0; t0 < TC; t0 += 16) {
    {
      int tn = t0 + 8;  // prefetch second half-group, 8 steps ahead
#pragma unroll
      for (int g = 0; g < 4; ++g) gB[g] = *(const uint4*)(gxb + (size_t)g * TC + tn);
    }
#pragma unroll
    for (int j = 0; j < 8; ++j) STEP(gA, t0 + j, j);
    {
      int tm = t0 + 16; if (tm > TC - 8) tm = TC - 8;  // clamp (values unused)
#pragma unroll
      for (int g = 0; g < 4; ++g) gA[g] = *(const uint4*)(gxb + (size_t)g * TC + tm);
    }
#pragma unroll
    for (int j = 0; j < 8; ++j) STEP(gB, t0 + 8 + j, j);
  }

  if (h1x && s == 0) h1x[(size_t)(TC - 1) * HID] = (f16)hprev;
  if (s == 0) {
    P.hst[b * HID + c] = (float)(f16)hprev;  // chunk chain uses f16-rounded h
    P.cst[b * HID + c] = cstate;
    if (P.fin) P.fin[b * HID + c] = hprev;
  }
}

extern "C" void kernel_launch(void* const* d_in, const int* in_sizes, int n_in,
                              void* d_out, int out_size, void* d_ws,
                              size_t ws_size, hipStream_t stream) {
  const float* x    = (const float*)d_in[0];
  const float* h0   = (const float*)d_in[1];
  const float* c0   = (const float*)d_in[2];
  const float* Wih0 = (const float*)d_in[3];
  const float* Whh0 = (const float*)d_in[4];
  const float* bih0 = (const float*)d_in[5];
  const float* bhh0 = (const float*)d_in[6];
  const float* Wih1 = (const float*)d_in[7];
  const float* Whh1 = (const float*)d_in[8];
  const float* bih1 = (const float*)d_in[9];
  const float* bhh1 = (const float*)d_in[10];

  char* w = (char*)d_ws;
  f16* Gx0 = (f16*)w;      w += (size_t)B_ * TC * NG * 2;   // 33.5 MB
  f16* Gx1 = (f16*)w;      w += (size_t)B_ * TC * NG * 2;   // 33.5 MB
  f16* h1  = (f16*)w;      w += (size_t)B_ * TC * HID * 2;  // 8.4 MB
  float* sH0 = (float*)w;  w += (size_t)B_ * HID * 4;
  float* sC0 = (float*)w;  w += (size_t)B_ * HID * 4;
  float* sH1 = (float*)w;  w += (size_t)B_ * HID * 4;
  float* sC1 = (float*)w;

  const dim3 ggrid(B_ * TC / 128, 8);  // (256, 8)

  auto l0args = [&](int cc) {
    RecArgs a;
    a.Gx = Gx0; a.Whh = Whh0;
    a.hin = cc == 0 ? h0 : sH0; a.cin = cc == 0 ? c0 : sC0;
    a.hst = sH0; a.cst = sC0; a.h1out = h1; a.fin = nullptr;
    return a;
  };
  auto l1args = [&](int cc) {
    RecArgs a;
    a.Gx = Gx1; a.Whh = Whh1;
    a.hin = cc == 0 ? h0 + B_ * HID : sH1; a.cin = cc == 0 ? c0 + B_ * HID : sC1;
    a.hst = sH1; a.cst = sC1; a.h1out = nullptr;
    a.fin = cc == NC - 1 ? (float*)d_out : nullptr;
    return a;
  };

  RecArgs dummy = {};

  // chunk 0, layer 0
  gemm_xw<KX0, false><<<ggrid, 256, 0, stream>>>(
      x + (size_t)0 * TC * KX0, (size_t)T_ * KX0, Wih0, bih0, bhh0, Gx0);
  lstm_rec2<<<B_, 256, 0, stream>>>(l0args(0), dummy, B_);

  for (int cc = 1; cc < NC; ++cc) {
    gemm_xw<HID, true><<<ggrid, 256, 0, stream>>>(h1, 0, Wih1, bih1, bhh1, Gx1);
    gemm_xw<KX0, false><<<ggrid, 256, 0, stream>>>(
        x + (size_t)cc * TC * KX0, (size_t)T_ * KX0, Wih0, bih0, bhh0, Gx0);
    lstm_rec2<<<2 * B_, 256, 0, stream>>>(l0args(cc), l1args(cc - 1), B_);
  }

  gemm_xw<HID, true><<<ggrid, 256, 0, stream>>>(h1, 0, Wih1, bih1, bhh1, Gx1);
  lstm_rec2<<<B_, 256, 0, stream>>>(l1args(NC - 1), dummy, B_);
}